// Round 27
// baseline (110.309 us; speedup 1.0000x reference)
//
#include <hip/hip_runtime.h>
#include <hip/hip_bf16.h>
#include <cstdint>

#define TB 8
#define TN 1024
#define TC 768
#define TH 12
#define THD 64
#define TM (TB*TN)          // 8192 rows
#define TNQKV (3*TC)        // 2304
// SCALE * log2(e) = 0.125 * 1.4426950408889634
#define QSCALE_LOG2E 0.18033688011112042f

typedef __attribute__((ext_vector_type(8))) short s16x8;
typedef __attribute__((ext_vector_type(4))) float f32x4;
typedef __attribute__((ext_vector_type(16))) float f32x16;
typedef __attribute__((ext_vector_type(2))) unsigned int u32x2;

__device__ __forceinline__ unsigned short f2bf(float f) {
    union { float f; unsigned int u; } v; v.f = f;
    unsigned int u = v.u;
    return (unsigned short)((u + 0x7FFFu + ((u >> 16) & 1u)) >> 16);
}

__device__ __forceinline__ float bf2f(unsigned short h) {
    union { float f; unsigned int u; } v; v.u = ((unsigned int)h) << 16;
    return v.f;
}

// packed f32x2 -> bf16x2 (RNE), single instruction on gfx950
__device__ __forceinline__ unsigned int cvt_pk_bf16(float lo, float hi) {
    unsigned int r;
    asm("v_cvt_pk_bf16_f32 %0, %1, %2" : "=v"(r) : "v"(lo), "v"(hi));
    return r;
}

__device__ __forceinline__ void gload_lds16(const unsigned short* g, unsigned short* l) {
    __builtin_amdgcn_global_load_lds(
        (const __attribute__((address_space(1))) unsigned int*)g,
        (__attribute__((address_space(3))) unsigned int*)l,
        16, 0, 0);
}

// ---------------- merged f32 -> bf16 conversion (3 tensors, one launch) ------
__global__ __launch_bounds__(256) void cvt3_kernel(
    const float* __restrict__ a, unsigned short* __restrict__ oa, int na,
    const float* __restrict__ b, unsigned short* __restrict__ ob, int nb,
    const float* __restrict__ c, unsigned short* __restrict__ oc, int nc)
{
    int i = blockIdx.x * blockDim.x + threadIdx.x;
    const float* src; unsigned short* dst; int idx;
    if (i < na)           { src = a; dst = oa; idx = i; }
    else if (i < na + nb) { src = b; dst = ob; idx = i - na; }
    else if (i < na + nb + nc) { src = c; dst = oc; idx = i - na - nb; }
    else return;
    f32x4 x0 = *(const f32x4*)(src + (size_t)idx * 8);
    f32x4 x1 = *(const f32x4*)(src + (size_t)idx * 8 + 4);
    s16x8 r;
    #pragma unroll
    for (int e = 0; e < 4; e++) r[e] = (short)f2bf(x0[e]);
    #pragma unroll
    for (int e = 0; e < 4; e++) r[4 + e] = (short)f2bf(x1[e]);
    *(s16x8*)(dst + (size_t)idx * 8) = r;
}

// ---------------- bf16 GEMM, C = A * B^T (+bias). BK=64, 32x32x16 MFMA -------
// Tile 128 x (WN*YF*32); waves WM x WN (WM*WN=4, 256 thr); per-wave
// (XF*32) x (YF*32). [rows][64 half] LDS tiles, chunk^(row&7) involution.
// 2-barrier schedule (r13-proven).
// VSPLIT (QKV only): tiles with col >= 1536 are V -> transposed vt[bh][d][k].
template<int XF, int YF, int WM, int WN, bool BIAS, bool OBF16, bool VSPLIT>
__global__ __launch_bounds__(256) void gemm_bt(
    const unsigned short* __restrict__ A,
    const unsigned short* __restrict__ Bm,
    void* __restrict__ Cout,
    const float* __restrict__ bias,
    unsigned short* __restrict__ vt,
    int M, int Nn, int K)
{
    constexpr int NBROWS = WN * YF * 32;     // B tile rows (= tile cols)
    __shared__ unsigned short As[128 * 64];
    __shared__ unsigned short Bs[NBROWS * 64];
    const int t = threadIdx.x;
    const int w = t >> 6, l = t & 63;
    const int wm = w / WN, wn = w % WN;
    const int bm = blockIdx.x, bn = blockIdx.y;
    const int l31 = l & 31, khi = l >> 5;
    const int r7 = l31 & 7;

    f32x16 acc[XF][YF] = {};

    const unsigned short* Ab = A + (size_t)bm * 128 * K;
    const unsigned short* Bb = Bm + (size_t)bn * NBROWS * K;

    for (int kt = 0; kt < K; kt += 64) {
        __syncthreads();
        #pragma unroll
        for (int j = 0; j < 4; j++) {
            const int s = j * 256 + t, row = s >> 3, c = s & 7;
            const int g = c ^ (row & 7);           // pre-permuted source chunk
            gload_lds16(Ab + (size_t)row * K + kt + g * 8, As + s * 8);
        }
        #pragma unroll
        for (int j = 0; j < NBROWS / 32; j++) {
            const int s = j * 256 + t, row = s >> 3, c = s & 7;
            const int g = c ^ (row & 7);
            gload_lds16(Bb + (size_t)row * K + kt + g * 8, Bs + s * 8);
        }
        __syncthreads();
        #pragma unroll
        for (int ks = 0; ks < 4; ks++) {
            const int ch = ((ks << 1) + khi) ^ r7;   // swizzled read chunk
            s16x8 af[XF], bf[YF];
            #pragma unroll
            for (int X = 0; X < XF; X++)
                af[X] = *(const s16x8*)(
                    As + (wm * (XF * 32) + X * 32 + l31) * 64 + ch * 8);
            #pragma unroll
            for (int Y = 0; Y < YF; Y++)
                bf[Y] = *(const s16x8*)(
                    Bs + (wn * (YF * 32) + Y * 32 + l31) * 64 + ch * 8);
            #pragma unroll
            for (int X = 0; X < XF; X++)
                #pragma unroll
                for (int Y = 0; Y < YF; Y++)
                    acc[X][Y] = __builtin_amdgcn_mfma_f32_32x32x16_bf16(
                        af[X], bf[Y], acc[X][Y], 0, 0, 0);
        }
    }

    // C/D layout [HW-verified m74/m101]: col = l31 (B-side), row = (reg&3) +
    // 8*(reg>>2) + 4*khi (A-side).
    const int r0 = bm * 128 + wm * (XF * 32);
    const int c0 = bn * (WN * YF * 32) + wn * (YF * 32);
    if constexpr (VSPLIT) {
        if (c0 >= 2 * TC) {
            // V tile: write transposed vt[bh][d][k]; reg&3 = 4 consecutive k
            #pragma unroll
            for (int X = 0; X < XF; X++) {
                const int rx = r0 + X * 32;
                const int bb = (rx >> 10) * TH;
                const int k0 = (rx & 1023) + 4 * khi;
                #pragma unroll
                for (int Y = 0; Y < YF; Y++) {
                    const int dg = c0 + Y * 32 + l31 - 2 * TC;   // 0..767
                    unsigned short* vp = vt + ((size_t)(bb + (dg >> 6)) << 16)
                                            + (dg & 63) * TN;
                    #pragma unroll
                    for (int g = 0; g < 4; g++) {
                        u32x2 r;
                        r[0] = cvt_pk_bf16(acc[X][Y][g * 4], acc[X][Y][g * 4 + 1]);
                        r[1] = cvt_pk_bf16(acc[X][Y][g * 4 + 2], acc[X][Y][g * 4 + 3]);
                        *(u32x2*)(vp + k0 + 8 * g) = r;
                    }
                }
            }
            return;
        }
    }
    if constexpr (OBF16) {
        unsigned short* O = (unsigned short*)Cout;
        #pragma unroll
        for (int X = 0; X < XF; X++)
            #pragma unroll
            for (int Y = 0; Y < YF; Y++) {
                const int cc = c0 + Y * 32 + l31;
                const int rb = r0 + X * 32 + 4 * khi;
                #pragma unroll
                for (int i = 0; i < 16; i++)
                    O[(size_t)(rb + (i & 3) + 8 * (i >> 2)) * Nn + cc] =
                        f2bf(acc[X][Y][i]);
            }
    } else {
        float* O = (float*)Cout;
        #pragma unroll
        for (int X = 0; X < XF; X++)
            #pragma unroll
            for (int Y = 0; Y < YF; Y++) {
                const int cc = c0 + Y * 32 + l31;
                const int rb = r0 + X * 32 + 4 * khi;
                float bv = 0.f;
                if constexpr (BIAS) bv = bias[cc];
                #pragma unroll
                for (int i = 0; i < 16; i++)
                    O[(size_t)(rb + (i & 3) + 8 * (i >> 2)) * Nn + cc] =
                        acc[X][Y][i] + bv;
            }
    }
}

// ---------------- Flash attention, swapped-QK^T, LDS-staged K/V --------------
// 8 waves x 16 q-rows = 128-q tile; KVBLK=64; K/V double-buffered in LDS.
// Shift-free softmax; lsum via ones-MFMA; T5 setprio. [r25-proven: ~34 us]
__global__ __launch_bounds__(512) void attn_kernel(
    const unsigned short* __restrict__ qkv,
    const unsigned short* __restrict__ vt,
    unsigned short* __restrict__ out)     // [8192][768] bf16
{
    const int bid = blockIdx.x;           // 0..767
    const int vid = (bid & 7) * 96 + (bid >> 3);
    const int bh = vid >> 3;              // 0..95
    const int qt = vid & 7;               // 0..7
    const int b = bh / TH, h = bh % TH;
    const int t = threadIdx.x, w = t >> 6, l = t & 63;
    const int lr = l & 15, lh = l >> 4;
    const int qbase = qt * 128 + w * 16;

    __shared__ unsigned short Kbuf[2][64 * 64];
    __shared__ unsigned short Vbuf[2][64 * 64];
    __shared__ unsigned short plds[8][16 * 64];  // swizzled; total LDS = 48 KB

    const unsigned short* kbase = qkv + (size_t)(b * TN) * TNQKV + TC + h * THD;
    const unsigned short* vtb = vt + (size_t)bh * THD * TN;

    // staging geometry: wave w covers rows 8w..8w+7 of both tiles (1 instr each)
    const int srow_lo = (l >> 3);              // 0..7 within 8-row group
    const int schunk = (l & 7) ^ srow_lo;      // pre-swizzled 16B-chunk (involution)
    const int srow = w * 8 + srow_lo;
    const int sdst = w * 512 + l * 8;          // = srow*64 + (l&7)*8

    // Q as B-operand fragments, pre-scaled by SCALE*log2e (so P = exp2(s))
    const unsigned short* qptr = qkv + (size_t)(b * TN + qbase + lr) * TNQKV + h * THD;
    s16x8 bq[2];
    #pragma unroll
    for (int cj = 0; cj < 2; cj++) {
        s16x8 raw = *(const s16x8*)(qptr + cj * 32 + lh * 8);
        #pragma unroll
        for (int e = 0; e < 8; e++)
            bq[cj][e] = (short)f2bf(bf2f((unsigned short)raw[e]) * QSCALE_LOG2E);
    }
    s16x8 av1;   // ones A-operand for lsum accumulator
    #pragma unroll
    for (int e = 0; e < 8; e++) av1[e] = (short)0x3F80;

    f32x4 o[5] = {};          // o[0..3]: O^T (q=lr, d=nd*16+lh*4+i); o[4]: lsum
    unsigned short* pw = plds[w];
    const int lr7 = lr & 7;

    // prologue: stage tile 0 into buf 0
    gload_lds16(kbase + (size_t)srow * TNQKV + schunk * 8, &Kbuf[0][sdst]);
    gload_lds16(vtb + (size_t)srow * TN + schunk * 8, &Vbuf[0][sdst]);
    __syncthreads();

    for (int it = 0; it < 16; it++) {
        const int kt = it * 64;
        const int cur = it & 1, nxt = cur ^ 1;
        // --- issue next tile's staging ---
        if (it + 1 < 16) {
            const int ktn = kt + 64;
            gload_lds16(kbase + (size_t)(ktn + srow) * TNQKV + schunk * 8, &Kbuf[nxt][sdst]);
            gload_lds16(vtb + (size_t)srow * TN + ktn + schunk * 8, &Vbuf[nxt][sdst]);
        }
        const unsigned short* Kc = Kbuf[cur];
        const unsigned short* Vc = Vbuf[cur];

        // --- S^T = K Q^T for 64k x 16q: lane gets s[q=lr][k=kk*16+lh*4+i] ---
        f32x4 s[4];
        __builtin_amdgcn_s_setprio(1);
        #pragma unroll
        for (int kk = 0; kk < 4; kk++) {
            const int r = kk * 16 + lr;
            s16x8 ak0 = *(const s16x8*)(Kc + r * 64 + ((lh ^ lr7) * 8));
            s16x8 ak1 = *(const s16x8*)(Kc + r * 64 + (((4 + lh) ^ lr7) * 8));
            f32x4 z = {0.f, 0.f, 0.f, 0.f};
            z = __builtin_amdgcn_mfma_f32_16x16x32_bf16(ak0, bq[0], z, 0, 0, 0);
            z = __builtin_amdgcn_mfma_f32_16x16x32_bf16(ak1, bq[1], z, 0, 0, 0);
            s[kk] = z;
        }
        __builtin_amdgcn_s_setprio(0);

        // --- shift-free softmax numerator: P = exp2(s), no max tracking ---
        #pragma unroll
        for (int kk = 0; kk < 4; kk++)
            #pragma unroll
            for (int i = 0; i < 4; i++)
                s[kk][i] = __builtin_amdgcn_exp2f(s[kk][i]);

        // --- P^T -> swizzled LDS [q=lr][k], cvt_pk 8B packed writes ---
        #pragma unroll
        for (int kk = 0; kk < 4; kk++) {
            u32x2 pk;
            pk[0] = cvt_pk_bf16(s[kk][0], s[kk][1]);
            pk[1] = cvt_pk_bf16(s[kk][2], s[kk][3]);
            const int wch = ((kk << 1) + (lh >> 1)) ^ lr7;
            *(u32x2*)(pw + lr * 64 + wch * 8 + (lh & 1) * 4) = pk;
        }
        // --- O^T += Vt P^T ; o[4] += ones P^T (= row sums of P) ---
        __builtin_amdgcn_s_setprio(1);
        #pragma unroll
        for (int ktile = 0; ktile < 2; ktile++) {
            const int rch = ((ktile << 2) + lh) ^ lr7;
            s16x8 bp = *(const s16x8*)(pw + lr * 64 + rch * 8);
            #pragma unroll
            for (int nd = 0; nd < 4; nd++) {
                const int d = nd * 16 + lr;
                s16x8 av = *(const s16x8*)(
                    Vc + d * 64 + ((((ktile << 2) + lh) ^ lr7) * 8));
                o[nd] = __builtin_amdgcn_mfma_f32_16x16x32_bf16(av, bp, o[nd], 0, 0, 0);
            }
            o[4] = __builtin_amdgcn_mfma_f32_16x16x32_bf16(av1, bp, o[4], 0, 0, 0);
        }
        __builtin_amdgcn_s_setprio(0);
        __syncthreads();   // drains staging vmcnt + protects buffer swap
    }

    // epilogue: lsum comes from the ones-accumulator (all regs equal)
    float inv = 1.f / o[4][0];
    unsigned short* op = out + (size_t)(b * TN + qbase + lr) * TC + h * THD;
    #pragma unroll
    for (int nd = 0; nd < 4; nd++) {
        u32x2 r;
        r[0] = cvt_pk_bf16(o[nd][0] * inv, o[nd][1] * inv);
        r[1] = cvt_pk_bf16(o[nd][2] * inv, o[nd][3] * inv);
        *(u32x2*)(op + nd * 16 + lh * 4) = r;
    }
}

extern "C" void kernel_launch(void* const* d_in, const int* in_sizes, int n_in,
                              void* d_out, int out_size, void* d_ws, size_t ws_size,
                              hipStream_t stream) {
    const float* x      = (const float*)d_in[0];
    const float* w_qkv  = (const float*)d_in[1];
    const float* w_proj = (const float*)d_in[2];
    const float* b_proj = (const float*)d_in[3];
    float* out = (float*)d_out;

    unsigned short* xb   = (unsigned short*)d_ws;
    unsigned short* wqb  = xb   + (size_t)TM * TC;
    unsigned short* wpb  = wqb  + (size_t)TNQKV * TC;
    unsigned short* qkvb = wpb  + (size_t)TC * TC;
    unsigned short* vtb  = qkvb + (size_t)TM * TNQKV;
    unsigned short* aob  = vtb  + (size_t)TB * TH * THD * TN;

    const int na = TM * TC / 8, nb = TNQKV * TC / 8, nc = TC * TC / 8;
    cvt3_kernel<<<(na + nb + nc + 255) / 256, 256, 0, stream>>>(
        x, xb, na, w_qkv, wqb, nb, w_proj, wpb, nc);

    // QKV GEMM: tile 128x192 (measured 49.0 us, r26) + fused V^T epilogue
    gemm_bt<2, 3, 2, 2, false, true, true><<<dim3(TM / 128, TNQKV / 192), 256, 0, stream>>>(
        xb, wqb, (void*)qkvb, nullptr, vtb, TM, TNQKV, TC);

    attn_kernel<<<768, 512, 0, stream>>>(qkvb, vtb, aob);

    // proj GEMM: tile 128x128 (r13 geometry, measured ~13 us)
    gemm_bt<2, 2, 2, 2, true, false, false><<<dim3(TM / 128, TC / 128), 256, 0, stream>>>(
        aob, wpb, (void*)out, b_proj, nullptr, TM, TC, TC);
}

// Round 28
// 108.462 us; speedup vs baseline: 1.0170x; 1.0170x over previous
//
#include <hip/hip_runtime.h>
#include <hip/hip_bf16.h>
#include <cstdint>

#define TB 8
#define TN 1024
#define TC 768
#define TH 12
#define THD 64
#define TM (TB*TN)          // 8192 rows
#define TNQKV (3*TC)        // 2304
// SCALE * log2(e) = 0.125 * 1.4426950408889634
#define QSCALE_LOG2E 0.18033688011112042f

typedef __attribute__((ext_vector_type(8))) short s16x8;
typedef __attribute__((ext_vector_type(4))) float f32x4;
typedef __attribute__((ext_vector_type(16))) float f32x16;
typedef __attribute__((ext_vector_type(2))) unsigned int u32x2;

__device__ __forceinline__ unsigned short f2bf(float f) {
    union { float f; unsigned int u; } v; v.f = f;
    unsigned int u = v.u;
    return (unsigned short)((u + 0x7FFFu + ((u >> 16) & 1u)) >> 16);
}

__device__ __forceinline__ float bf2f(unsigned short h) {
    union { float f; unsigned int u; } v; v.u = ((unsigned int)h) << 16;
    return v.f;
}

// packed f32x2 -> bf16x2 (RNE), single instruction on gfx950
__device__ __forceinline__ unsigned int cvt_pk_bf16(float lo, float hi) {
    unsigned int r;
    asm("v_cvt_pk_bf16_f32 %0, %1, %2" : "=v"(r) : "v"(lo), "v"(hi));
    return r;
}

__device__ __forceinline__ void gload_lds16(const unsigned short* g, unsigned short* l) {
    __builtin_amdgcn_global_load_lds(
        (const __attribute__((address_space(1))) unsigned int*)g,
        (__attribute__((address_space(3))) unsigned int*)l,
        16, 0, 0);
}

// ---------------- merged f32 -> bf16 conversion (3 tensors, one launch) ------
__global__ __launch_bounds__(256) void cvt3_kernel(
    const float* __restrict__ a, unsigned short* __restrict__ oa, int na,
    const float* __restrict__ b, unsigned short* __restrict__ ob, int nb,
    const float* __restrict__ c, unsigned short* __restrict__ oc, int nc)
{
    int i = blockIdx.x * blockDim.x + threadIdx.x;
    const float* src; unsigned short* dst; int idx;
    if (i < na)           { src = a; dst = oa; idx = i; }
    else if (i < na + nb) { src = b; dst = ob; idx = i - na; }
    else if (i < na + nb + nc) { src = c; dst = oc; idx = i - na - nb; }
    else return;
    f32x4 x0 = *(const f32x4*)(src + (size_t)idx * 8);
    f32x4 x1 = *(const f32x4*)(src + (size_t)idx * 8 + 4);
    s16x8 r;
    #pragma unroll
    for (int e = 0; e < 4; e++) r[e] = (short)f2bf(x0[e]);
    #pragma unroll
    for (int e = 0; e < 4; e++) r[4 + e] = (short)f2bf(x1[e]);
    *(s16x8*)(dst + (size_t)idx * 8) = r;
}

// ---------------- bf16 GEMM, C = A * B^T (+bias). BK=64, 32x32x16 MFMA -------
// [128 row][64 half] LDS tiles, chunk ^ (row&7) involution. 2-barrier
// schedule; 4 waves; per-wave 64x64 out (2x2 frags). [r13-proven: 50.3 us QKV]
// VSPLIT (QKV only): tiles with bn>=12 are V -> write transposed vt[bh][d][k].
template<bool BIAS, bool OBF16, bool VSPLIT>
__global__ __launch_bounds__(256) void gemm_bt(
    const unsigned short* __restrict__ A,
    const unsigned short* __restrict__ Bm,
    void* __restrict__ Cout,
    const float* __restrict__ bias,
    unsigned short* __restrict__ vt,
    int M, int Nn, int K)
{
    __shared__ unsigned short As[128 * 64];
    __shared__ unsigned short Bs[128 * 64];
    const int t = threadIdx.x;
    const int w = t >> 6, l = t & 63;
    const int wm = w >> 1, wn = w & 1;   // 2x2 wave grid, 64x64 out per wave
    const int bm = blockIdx.x, bn = blockIdx.y;
    const int l31 = l & 31, khi = l >> 5;
    const int r7 = l31 & 7;

    f32x16 acc00 = {}, acc01 = {}, acc10 = {}, acc11 = {};

    const unsigned short* Ab = A + (size_t)bm * 128 * K;
    const unsigned short* Bb = Bm + (size_t)bn * 128 * K;

    for (int kt = 0; kt < K; kt += 64) {
        __syncthreads();
        #pragma unroll
        for (int j = 0; j < 4; j++) {
            const int s = j * 256 + t, row = s >> 3, c = s & 7;
            const int g = c ^ (row & 7);           // pre-permuted source chunk
            gload_lds16(Ab + (size_t)row * K + kt + g * 8, As + s * 8);
            gload_lds16(Bb + (size_t)row * K + kt + g * 8, Bs + s * 8);
        }
        __syncthreads();
        #pragma unroll
        for (int ks = 0; ks < 4; ks++) {
            const int ch = ((ks << 1) + khi) ^ r7;   // swizzled read chunk
            const unsigned short* Ar = As + (wm * 64 + l31) * 64 + ch * 8;
            const unsigned short* Br = Bs + (wn * 64 + l31) * 64 + ch * 8;
            s16x8 a0 = *(const s16x8*)(Ar);
            s16x8 a1 = *(const s16x8*)(Ar + 32 * 64);
            s16x8 b0 = *(const s16x8*)(Br);
            s16x8 b1 = *(const s16x8*)(Br + 32 * 64);
            acc00 = __builtin_amdgcn_mfma_f32_32x32x16_bf16(a0, b0, acc00, 0, 0, 0);
            acc01 = __builtin_amdgcn_mfma_f32_32x32x16_bf16(a0, b1, acc01, 0, 0, 0);
            acc10 = __builtin_amdgcn_mfma_f32_32x32x16_bf16(a1, b0, acc10, 0, 0, 0);
            acc11 = __builtin_amdgcn_mfma_f32_32x32x16_bf16(a1, b1, acc11, 0, 0, 0);
        }
    }

    const int r0 = bm * 128 + wm * 64;
    const int c0 = bn * 128 + wn * 64;
    f32x16 accs[2][2] = {{acc00, acc01}, {acc10, acc11}};
    if constexpr (VSPLIT) {
        if (bn >= 12) {
            // V tile: write transposed vt[bh][d][k]; reg&3 = 4 consecutive k
            const int bb = (r0 >> 10) * TH;
            #pragma unroll
            for (int X = 0; X < 2; X++)
                #pragma unroll
                for (int Y = 0; Y < 2; Y++) {
                    const int dg = c0 + Y * 32 + l31 - 2 * TC;   // 0..767
                    unsigned short* vp = vt + ((size_t)(bb + (dg >> 6)) << 16)
                                            + (dg & 63) * TN;
                    const int k0 = (r0 & 1023) + X * 32 + 4 * khi;
                    #pragma unroll
                    for (int g = 0; g < 4; g++) {
                        u32x2 r;
                        r[0] = cvt_pk_bf16(accs[X][Y][g * 4], accs[X][Y][g * 4 + 1]);
                        r[1] = cvt_pk_bf16(accs[X][Y][g * 4 + 2], accs[X][Y][g * 4 + 3]);
                        *(u32x2*)(vp + k0 + 8 * g) = r;
                    }
                }
            return;
        }
    }
    if constexpr (OBF16) {
        unsigned short* O = (unsigned short*)Cout;
        #pragma unroll
        for (int X = 0; X < 2; X++)
            #pragma unroll
            for (int Y = 0; Y < 2; Y++) {
                const int cc = c0 + Y * 32 + l31;
                const int rb = r0 + X * 32 + 4 * khi;
                #pragma unroll
                for (int i = 0; i < 16; i++)
                    O[(size_t)(rb + (i & 3) + 8 * (i >> 2)) * Nn + cc] =
                        f2bf(accs[X][Y][i]);
            }
    } else {
        float* O = (float*)Cout;
        #pragma unroll
        for (int X = 0; X < 2; X++)
            #pragma unroll
            for (int Y = 0; Y < 2; Y++) {
                const int cc = c0 + Y * 32 + l31;
                const int rb = r0 + X * 32 + 4 * khi;
                float bv = 0.f;
                if constexpr (BIAS) bv = bias[cc];
                #pragma unroll
                for (int i = 0; i < 16; i++)
                    O[(size_t)(rb + (i & 3) + 8 * (i >> 2)) * Nn + cc] =
                        accs[X][Y][i] + bv;
            }
    }
}

// ---------------- Flash attention, swapped-QK^T, LDS-staged K/V --------------
// 8 waves x 16 q-rows = 128-q tile; KVBLK=64; K/V double-buffered in LDS.
// Shift-free softmax (bounded scores, softmax shift-invariance); lsum via
// ones-MFMA accumulator; setprio(1) around MFMA clusters (T5).
// [r20/r25-proven best: ~34 us; 8-wave TLP is the binding resource]
__global__ __launch_bounds__(512) void attn_kernel(
    const unsigned short* __restrict__ qkv,
    const unsigned short* __restrict__ vt,
    unsigned short* __restrict__ out)     // [8192][768] bf16
{
    const int bid = blockIdx.x;           // 0..767
    const int vid = (bid & 7) * 96 + (bid >> 3);
    const int bh = vid >> 3;              // 0..95
    const int qt = vid & 7;               // 0..7
    const int b = bh / TH, h = bh % TH;
    const int t = threadIdx.x, w = t >> 6, l = t & 63;
    const int lr = l & 15, lh = l >> 4;
    const int qbase = qt * 128 + w * 16;

    __shared__ unsigned short Kbuf[2][64 * 64];
    __shared__ unsigned short Vbuf[2][64 * 64];
    __shared__ unsigned short plds[8][16 * 64];  // swizzled; total LDS = 48 KB

    const unsigned short* kbase = qkv + (size_t)(b * TN) * TNQKV + TC + h * THD;
    const unsigned short* vtb = vt + (size_t)bh * THD * TN;

    // staging geometry: wave w covers rows 8w..8w+7 of both tiles (1 instr each)
    const int srow_lo = (l >> 3);              // 0..7 within 8-row group
    const int schunk = (l & 7) ^ srow_lo;      // pre-swizzled 16B-chunk (involution)
    const int srow = w * 8 + srow_lo;
    const int sdst = w * 512 + l * 8;          // = srow*64 + (l&7)*8

    // Q as B-operand fragments, pre-scaled by SCALE*log2e (so P = exp2(s))
    const unsigned short* qptr = qkv + (size_t)(b * TN + qbase + lr) * TNQKV + h * THD;
    s16x8 bq[2];
    #pragma unroll
    for (int cj = 0; cj < 2; cj++) {
        s16x8 raw = *(const s16x8*)(qptr + cj * 32 + lh * 8);
        #pragma unroll
        for (int e = 0; e < 8; e++)
            bq[cj][e] = (short)f2bf(bf2f((unsigned short)raw[e]) * QSCALE_LOG2E);
    }
    s16x8 av1;   // ones A-operand for lsum accumulator
    #pragma unroll
    for (int e = 0; e < 8; e++) av1[e] = (short)0x3F80;

    f32x4 o[5] = {};          // o[0..3]: O^T (q=lr, d=nd*16+lh*4+i); o[4]: lsum
    unsigned short* pw = plds[w];
    const int lr7 = lr & 7;

    // prologue: stage tile 0 into buf 0
    gload_lds16(kbase + (size_t)srow * TNQKV + schunk * 8, &Kbuf[0][sdst]);
    gload_lds16(vtb + (size_t)srow * TN + schunk * 8, &Vbuf[0][sdst]);
    __syncthreads();

    for (int it = 0; it < 16; it++) {
        const int kt = it * 64;
        const int cur = it & 1, nxt = cur ^ 1;
        // --- issue next tile's staging ---
        if (it + 1 < 16) {
            const int ktn = kt + 64;
            gload_lds16(kbase + (size_t)(ktn + srow) * TNQKV + schunk * 8, &Kbuf[nxt][sdst]);
            gload_lds16(vtb + (size_t)srow * TN + ktn + schunk * 8, &Vbuf[nxt][sdst]);
        }
        const unsigned short* Kc = Kbuf[cur];
        const unsigned short* Vc = Vbuf[cur];

        // --- S^T = K Q^T for 64k x 16q: lane gets s[q=lr][k=kk*16+lh*4+i] ---
        f32x4 s[4];
        __builtin_amdgcn_s_setprio(1);
        #pragma unroll
        for (int kk = 0; kk < 4; kk++) {
            const int r = kk * 16 + lr;
            s16x8 ak0 = *(const s16x8*)(Kc + r * 64 + ((lh ^ lr7) * 8));
            s16x8 ak1 = *(const s16x8*)(Kc + r * 64 + (((4 + lh) ^ lr7) * 8));
            f32x4 z = {0.f, 0.f, 0.f, 0.f};
            z = __builtin_amdgcn_mfma_f32_16x16x32_bf16(ak0, bq[0], z, 0, 0, 0);
            z = __builtin_amdgcn_mfma_f32_16x16x32_bf16(ak1, bq[1], z, 0, 0, 0);
            s[kk] = z;
        }
        __builtin_amdgcn_s_setprio(0);

        // --- shift-free softmax numerator: P = exp2(s), no max tracking ---
        #pragma unroll
        for (int kk = 0; kk < 4; kk++)
            #pragma unroll
            for (int i = 0; i < 4; i++)
                s[kk][i] = __builtin_amdgcn_exp2f(s[kk][i]);

        // --- P^T -> swizzled LDS [q=lr][k], cvt_pk 8B packed writes ---
        #pragma unroll
        for (int kk = 0; kk < 4; kk++) {
            u32x2 pk;
            pk[0] = cvt_pk_bf16(s[kk][0], s[kk][1]);
            pk[1] = cvt_pk_bf16(s[kk][2], s[kk][3]);
            const int wch = ((kk << 1) + (lh >> 1)) ^ lr7;
            *(u32x2*)(pw + lr * 64 + wch * 8 + (lh & 1) * 4) = pk;
        }
        // --- O^T += Vt P^T ; o[4] += ones P^T (= row sums of P) ---
        __builtin_amdgcn_s_setprio(1);
        #pragma unroll
        for (int ktile = 0; ktile < 2; ktile++) {
            const int rch = ((ktile << 2) + lh) ^ lr7;
            s16x8 bp = *(const s16x8*)(pw + lr * 64 + rch * 8);
            #pragma unroll
            for (int nd = 0; nd < 4; nd++) {
                const int d = nd * 16 + lr;
                s16x8 av = *(const s16x8*)(
                    Vc + d * 64 + ((((ktile << 2) + lh) ^ lr7) * 8));
                o[nd] = __builtin_amdgcn_mfma_f32_16x16x32_bf16(av, bp, o[nd], 0, 0, 0);
            }
            o[4] = __builtin_amdgcn_mfma_f32_16x16x32_bf16(av1, bp, o[4], 0, 0, 0);
        }
        __builtin_amdgcn_s_setprio(0);
        __syncthreads();   // drains staging vmcnt + protects buffer swap
    }

    // epilogue: lsum comes from the ones-accumulator (all regs equal)
    float inv = 1.f / o[4][0];
    unsigned short* op = out + (size_t)(b * TN + qbase + lr) * TC + h * THD;
    #pragma unroll
    for (int nd = 0; nd < 4; nd++) {
        u32x2 r;
        r[0] = cvt_pk_bf16(o[nd][0] * inv, o[nd][1] * inv);
        r[1] = cvt_pk_bf16(o[nd][2] * inv, o[nd][3] * inv);
        *(u32x2*)(op + nd * 16 + lh * 4) = r;
    }
}

extern "C" void kernel_launch(void* const* d_in, const int* in_sizes, int n_in,
                              void* d_out, int out_size, void* d_ws, size_t ws_size,
                              hipStream_t stream) {
    const float* x      = (const float*)d_in[0];
    const float* w_qkv  = (const float*)d_in[1];
    const float* w_proj = (const float*)d_in[2];
    const float* b_proj = (const float*)d_in[3];
    float* out = (float*)d_out;

    unsigned short* xb   = (unsigned short*)d_ws;
    unsigned short* wqb  = xb   + (size_t)TM * TC;
    unsigned short* wpb  = wqb  + (size_t)TNQKV * TC;
    unsigned short* qkvb = wpb  + (size_t)TC * TC;
    unsigned short* vtb  = qkvb + (size_t)TM * TNQKV;
    unsigned short* aob  = vtb  + (size_t)TB * TH * THD * TN;

    const int na = TM * TC / 8, nb = TNQKV * TC / 8, nc = TC * TC / 8;
    cvt3_kernel<<<(na + nb + nc + 255) / 256, 256, 0, stream>>>(
        x, xb, na, w_qkv, wqb, nb, w_proj, wpb, nc);

    // QKV GEMM (r13 structure) + fused V-transpose epilogue
    gemm_bt<false, true, true><<<dim3(TM / 128, TNQKV / 128), 256, 0, stream>>>(
        xb, wqb, (void*)qkvb, nullptr, vtb, TM, TNQKV, TC);

    attn_kernel<<<768, 512, 0, stream>>>(qkvb, vtb, aob);

    // proj GEMM (r13 structure)
    gemm_bt<true, false, false><<<dim3(TM / 128, TC / 128), 256, 0, stream>>>(
        aob, wpb, (void*)out, b_proj, nullptr, TM, TC, TC);
}